// Round 10
// baseline (1569.629 us; speedup 1.0000x reference)
//
#include <hip/hip_runtime.h>
#include <stdint.h>

#define NB 128   // batch
#define NT 512   // time steps
#define NI 256   // input dim
#define NH 512   // hidden dim
#define NO 256   // output dim

// ---------- bf16 helpers ----------
__device__ __forceinline__ uint16_t f2bf(float x) {
  uint32_t u = __float_as_uint(x);
  return (uint16_t)((u + 0x7fffu + ((u >> 16) & 1u)) >> 16);
}
__device__ __forceinline__ uint32_t pack2bf(float a, float b) {
  return (uint32_t)f2bf(a) | ((uint32_t)f2bf(b) << 16);
}

__device__ __forceinline__ float fast_tanh(float x) {
  float e = __expf(2.0f * x);
#if __has_builtin(__builtin_amdgcn_rcpf)
  return 1.0f - 2.0f * __builtin_amdgcn_rcpf(e + 1.0f);
#else
  return 1.0f - 2.0f / (e + 1.0f);
#endif
}

typedef __bf16 bf16x8 __attribute__((ext_vector_type(8)));
typedef float f32x4 __attribute__((ext_vector_type(4)));

__device__ __forceinline__ f32x4 mfma16(bf16x8 a, uint4 b, f32x4 c) {
  return __builtin_amdgcn_mfma_f32_16x16x32_bf16(a, __builtin_bit_cast(bf16x8, b), c, 0, 0, 0);
}
__device__ __forceinline__ f32x4 mfma16_ab(uint4 a, bf16x8 b, f32x4 c) {
  return __builtin_amdgcn_mfma_f32_16x16x32_bf16(__builtin_bit_cast(bf16x8, a), b, c, 0, 0, 0);
}

// ---------- kernel 0: pack W_hh B-frags; Wih->frag order; transpose W_out; bias sum ----------
// B-frag quad q = u*16 + tk (u=n-tile 0..3, tk=k-tile 0..15):
//   n = (t>>6)*64 + u*16 + (t&15), k = tk*32 + ((t>>4)&3)*8 + j, value W_hh[n][k].
// Stored WB[q*512 + t]; recur holds ALL 64 quads in registers.
// xproj B-frag WihF[(U*8+k0)*64 + l]: row n=U*16+(l&15), k=k0*32+(l>>4)*8+j.
__global__ __launch_bounds__(256) void prep_kernel(const float* __restrict__ Whh,
                                                   const float* __restrict__ Wih,
                                                   const float* __restrict__ Wout,
                                                   const float* __restrict__ bih,
                                                   const float* __restrict__ bhh,
                                                   uint4* __restrict__ WB,
                                                   float* __restrict__ WoT,
                                                   uint4* __restrict__ WihF,
                                                   float* __restrict__ BS) {
  int idx = blockIdx.x * 256 + threadIdx.x;
  if (idx < 32768) {                       // W_hh B-fragments
    int q = idx >> 9, t = idx & 511;
    int u = q >> 4, tk = q & 15;
    int n = (t >> 6) * 64 + u * 16 + (t & 15);
    int kb = tk * 32 + ((t >> 4) & 3) * 8;
    const float* row = Whh + (size_t)n * NH + kb;
    float4 f0 = *(const float4*)row;
    float4 f1 = *(const float4*)(row + 4);
    uint4 wq;
    wq.x = pack2bf(f0.x, f0.y);
    wq.y = pack2bf(f0.z, f0.w);
    wq.z = pack2bf(f1.x, f1.y);
    wq.w = pack2bf(f1.z, f1.w);
    WB[idx] = wq;
  } else if (idx < 49152) {                // Wih B-fragments (for xproj)
    int i = idx - 32768;
    int l = i & 63;
    int uk = i >> 6;
    int k0 = uk & 7, u = uk >> 3;
    int n = u * 16 + (l & 15);
    int kb = k0 * 32 + (l >> 4) * 8;
    const float* row = Wih + (size_t)n * NI + kb;
    float4 f0 = *(const float4*)row;
    float4 f1 = *(const float4*)(row + 4);
    uint4 wq;
    wq.x = pack2bf(f0.x, f0.y);
    wq.y = pack2bf(f0.z, f0.w);
    wq.z = pack2bf(f1.x, f1.y);
    wq.w = pack2bf(f1.z, f1.w);
    WihF[i] = wq;
  } else if (idx < 81920) {                // W_out transpose (fp32)
    int i = idx - 49152;
    int o4 = (i & 63) * 4;
    int k = i >> 6;
    float4 v;
    v.x = Wout[(size_t)(o4 + 0) * NH + k];
    v.y = Wout[(size_t)(o4 + 1) * NH + k];
    v.z = Wout[(size_t)(o4 + 2) * NH + k];
    v.w = Wout[(size_t)(o4 + 3) * NH + k];
    *(float4*)&WoT[(size_t)k * NO + o4] = v;
  } else if (idx < 82432) {                // bias sum
    int n = idx - 81920;
    BS[n] = bih[n] + bhh[n];
  }
}

// ---------- kernel 1: x_proj GEMM — A staged once via LDS, B in AGPRs ----------
// 256 WGs x 256 thr (4 waves). Wave w owns n in [w*128, w*128+128) (8 n-tiles,
// 64 B-quads in regs, loaded once). 16 m-tiles/WG: A m-tile (16x256 fp32)
// staged to LDS as packed bf16 rows (528-B stride -> <=2-way read conflicts),
// double-buffered, 1 barrier per m-tile. A read ONCE from HBM.
#define XMT 16
#define AROW 528   // bytes per staged row (512 + 16 pad)
__global__ __launch_bounds__(256) void xproj_kernel(const float* __restrict__ A,
                                                    const uint4* __restrict__ WihF,
                                                    const float* __restrict__ BS,
                                                    uint16_t* __restrict__ XP) {
  __shared__ __align__(16) uint8_t Asm[2][16 * AROW];
  const int tid = threadIdx.x;
  const int w = tid >> 6;
  const int l = tid & 63;
  const int sl = l & 15, quad = l >> 4;
  const int mt0 = blockIdx.x * XMT;
  const int srow = tid >> 4;     // staging row 0..15
  const int sseg = tid & 15;     // staging segment (16 floats)

  uint4 Wb[64];
#pragma unroll
  for (int u8 = 0; u8 < 8; ++u8)
#pragma unroll
    for (int k0 = 0; k0 < 8; ++k0)
      Wb[u8 * 8 + k0] = WihF[(size_t)((w * 8 + u8) * 8 + k0) * 64 + l];

  float4 bs[8];
#pragma unroll
  for (int u8 = 0; u8 < 8; ++u8)
    bs[u8] = *(const float4*)(BS + (w * 8 + u8) * 16 + quad * 4);

  // stage first m-tile
  {
    const float* ar = A + (size_t)(mt0 * 16 + srow) * NI + sseg * 16;
    float4 f0 = *(const float4*)ar, f1 = *(const float4*)(ar + 4);
    float4 f2 = *(const float4*)(ar + 8), f3 = *(const float4*)(ar + 12);
    uint4 p0, p1;
    p0.x = pack2bf(f0.x, f0.y); p0.y = pack2bf(f0.z, f0.w);
    p0.z = pack2bf(f1.x, f1.y); p0.w = pack2bf(f1.z, f1.w);
    p1.x = pack2bf(f2.x, f2.y); p1.y = pack2bf(f2.z, f2.w);
    p1.z = pack2bf(f3.x, f3.y); p1.w = pack2bf(f3.z, f3.w);
    uint8_t* dst = &Asm[0][srow * AROW + sseg * 32];
    *(uint4*)dst = p0;
    *(uint4*)(dst + 16) = p1;
  }
  __syncthreads();

  for (int i = 0; i < XMT; ++i) {
    const int bb = i & 1;
    if (i + 1 < XMT) {   // stage next into other buffer (prev reads done at last barrier)
      const float* ar = A + (size_t)((mt0 + i + 1) * 16 + srow) * NI + sseg * 16;
      float4 f0 = *(const float4*)ar, f1 = *(const float4*)(ar + 4);
      float4 f2 = *(const float4*)(ar + 8), f3 = *(const float4*)(ar + 12);
      uint4 p0, p1;
      p0.x = pack2bf(f0.x, f0.y); p0.y = pack2bf(f0.z, f0.w);
      p0.z = pack2bf(f1.x, f1.y); p0.w = pack2bf(f1.z, f1.w);
      p1.x = pack2bf(f2.x, f2.y); p1.y = pack2bf(f2.z, f2.w);
      p1.z = pack2bf(f3.x, f3.y); p1.w = pack2bf(f3.z, f3.w);
      uint8_t* dst = &Asm[bb ^ 1][srow * AROW + sseg * 32];
      *(uint4*)dst = p0;
      *(uint4*)(dst + 16) = p1;
    }

    f32x4 acc[8] = {};
    const uint8_t* abase = &Asm[bb][sl * AROW + quad * 16];
#pragma unroll
    for (int k0 = 0; k0 < 8; ++k0) {
      bf16x8 a = *(const bf16x8*)(abase + k0 * 64);
#pragma unroll
      for (int u8 = 0; u8 < 8; ++u8)
        acc[u8] = mfma16_ab(Wb[u8 * 8 + k0], a, acc[u8]);
    }
    uint16_t* xrow = XP + (size_t)((mt0 + i) * 16 + sl) * NH + w * 128 + quad * 4;
#pragma unroll
    for (int u8 = 0; u8 < 8; ++u8) {
      uint2 pw;
      pw.x = pack2bf(acc[u8][0] + bs[u8].x, acc[u8][1] + bs[u8].y);
      pw.y = pack2bf(acc[u8][2] + bs[u8].z, acc[u8][3] + bs[u8].w);
      *(uint2*)(xrow + u8 * 16) = pw;
    }
    __syncthreads();
  }
}

// ---------- kernel 2: recurrence via MFMA, W_hh FULLY register-resident ----------
// 128 WGs x 512 thr (8 waves, 2/SIMD). Wave w owns outputs [w*64, w*64+64):
// 4 n-tiles x 16 k-tiles; all 64 B-quads in registers (AGPR), no LDS weights.
// A-replication trick: every lane's A-frag = h[tk*32+quad*8+j] -> D rows = y.
__global__ __launch_bounds__(512, 2) void recur_kernel(const uint4* __restrict__ WB,
                                                       const float* __restrict__ WoT,
                                                       const uint16_t* __restrict__ XP,
                                                       const float* __restrict__ h0,
                                                       const float* __restrict__ bout,
                                                       float* __restrict__ out) {
  __shared__ __align__(16) uint16_t h2[2][NH];   // 2 KB: bf16 h, double-buffered
  __shared__ float hsf[NH];                      // 2 KB: fp32 h for readout
  const int t = threadIdx.x;
  const int b = blockIdx.x;
  const int w = t >> 6;
  const int sl = t & 15, quad = (t >> 4) & 3;
  const int myn = w * 64 + quad * 16 + sl;       // h element this lane owns
  const float invT = 1.0f / (float)NT;

  uint4 Wr[64];
#pragma unroll
  for (int q = 0; q < 64; ++q) Wr[q] = WB[q * 512 + t];

  float hj = h0[myn];
  h2[0][myn] = f2bf(hj);
  __syncthreads();

  const uint16_t* xpb = XP + (size_t)b * NT * NH + myn;

  for (int ts = 0; ts < NT; ++ts) {
    const int cur = ts & 1;
    float xpj = __uint_as_float((uint32_t)xpb[(size_t)ts * NH] << 16);

    const uint16_t* hbuf = h2[cur];
    f32x4 acc0 = {}, acc1 = {}, acc2 = {}, acc3 = {};
#pragma unroll
    for (int tk = 0; tk < 16; ++tk) {
      bf16x8 hfrag = *(const bf16x8*)(hbuf + tk * 32 + quad * 8);  // quad-broadcast
      acc0 = mfma16(hfrag, Wr[tk], acc0);
      acc1 = mfma16(hfrag, Wr[16 + tk], acc1);
      acc2 = mfma16(hfrag, Wr[32 + tk], acc2);
      acc3 = mfma16(hfrag, Wr[48 + tk], acc3);
    }
    float y = (quad == 0) ? acc0[0] : (quad == 1) ? acc1[0] : (quad == 2) ? acc2[0] : acc3[0];
    float hnew = fmaf(fast_tanh(xpj + y), invT, hj);
    hj = hnew;
    h2[cur ^ 1][myn] = f2bf(hnew);
    __syncthreads();
  }

  hsf[myn] = hj;
  __syncthreads();

  if (t < NO) {
    float c0 = 0.f, c1 = 0.f;
#pragma unroll 4
    for (int k = 0; k < NH; k += 2) {
      c0 = fmaf(WoT[(size_t)k * NO + t], hsf[k], c0);
      c1 = fmaf(WoT[(size_t)(k + 1) * NO + t], hsf[k + 1], c1);
    }
    out[(size_t)b * NO + t] = c0 + c1 + bout[t];
  }
}

// ---------- launch ----------
extern "C" void kernel_launch(void* const* d_in, const int* in_sizes, int n_in,
                              void* d_out, int out_size, void* d_ws, size_t ws_size,
                              hipStream_t stream) {
  const float* inputs = (const float*)d_in[0];
  const float* Wih    = (const float*)d_in[1];
  const float* bih    = (const float*)d_in[2];
  const float* Whh    = (const float*)d_in[3];
  const float* bhh    = (const float*)d_in[4];
  const float* Wout   = (const float*)d_in[5];
  const float* bout   = (const float*)d_in[6];
  const float* h0     = (const float*)d_in[7];
  float* out = (float*)d_out;

  char* ws = (char*)d_ws;
  uint4*    WB   = (uint4*)ws;                          // 512 KB: W_hh B-frags
  float*    WoT  = (float*)(ws + (512u << 10));         // 512 KB: W_out^T
  uint4*    WihF = (uint4*)(ws + (1024u << 10));        // 256 KB: Wih B-frags
  float*    BS   = (float*)(ws + (1280u << 10));        // 2 KB: bias sum
  uint16_t* XP   = (uint16_t*)(ws + (1536u << 10));     // 64 MB: x_proj bf16

  hipLaunchKernelGGL(prep_kernel, dim3(322), dim3(256), 0, stream,
                     Whh, Wih, Wout, bih, bhh, WB, WoT, WihF, BS);
  hipLaunchKernelGGL(xproj_kernel, dim3(NB * NT / (XMT * 16)), dim3(256), 0, stream,
                     inputs, WihF, BS, XP);
  hipLaunchKernelGGL(recur_kernel, dim3(NB), dim3(512), 0, stream,
                     WB, WoT, XP, h0, bout, out);
}